// Round 6
// baseline (263.220 us; speedup 1.0000x reference)
//
#include <hip/hip_runtime.h>
#include <stdint.h>

typedef unsigned short u16;
typedef __bf16 bf16x8 __attribute__((ext_vector_type(8)));
typedef __bf16 bf16x2 __attribute__((ext_vector_type(2)));
typedef short s16x4 __attribute__((ext_vector_type(4)));
typedef float f32x4 __attribute__((ext_vector_type(4)));

typedef __attribute__((address_space(1))) void gvoid_t;
typedef __attribute__((address_space(3))) void lvoid_t;

struct alignas(16) U128 { uint32_t x, y, z, w; };
struct alignas(16) F128 { float x, y, z, w; };
struct alignas(8)  U64v { uint32_t x, y; };

__device__ __forceinline__ void gld16(const u16* g, u16* lds) {
  __builtin_amdgcn_global_load_lds((gvoid_t*)const_cast<u16*>(g),
                                   (lvoid_t*)lds, 16, 0, 0);
}

__device__ __forceinline__ u16 f2bf(float f) {
  uint32_t u = __builtin_bit_cast(uint32_t, f);
  u += 0x7FFFu + ((u >> 16) & 1u);   // RNE
  return (u16)(u >> 16);
}
__device__ __forceinline__ float bf2f(u16 h) {
  return __builtin_bit_cast(float, (uint32_t)h << 16);
}
__device__ __forceinline__ bf16x8 ldfrag(const u16* p) {
  U128 u = *reinterpret_cast<const U128*>(p);
  return __builtin_bit_cast(bf16x8, u);
}
// pack two f32 -> bf16x2 dword via HW cvt (compiler emits v_cvt_pk_bf16_f32)
__device__ __forceinline__ uint32_t pkbf(float a, float b) {
  bf16x2 v;
  v[0] = (__bf16)a;
  v[1] = (__bf16)b;
  return __builtin_bit_cast(uint32_t, v);
}

// raw v_exp_f32 (exp2) — scores bounded (|s|<~10), no denormal concerns
__device__ __forceinline__ float EXP2(float x) { return __builtin_amdgcn_exp2f(x); }

// ---------------- fp32 -> bf16 convert (x) ----------------
__global__ void cvt_f32_bf16(const float* __restrict__ in, u16* __restrict__ out) {
  int i = (blockIdx.x * 256 + threadIdx.x) * 4;
  F128 v = *reinterpret_cast<const F128*>(in + i);
  U64v o;
  o.x = (uint32_t)f2bf(v.x) | ((uint32_t)f2bf(v.y) << 16);
  o.y = (uint32_t)f2bf(v.z) | ((uint32_t)f2bf(v.w) << 16);
  *reinterpret_cast<U64v*>(out + i) = o;
}

// ---------------- transpose + convert weights: W (K x N f32) -> Wt (N x K bf16) ----
__global__ void transpose_cvt(const float* __restrict__ W, u16* __restrict__ Wt,
                              int K, int N) {
  __shared__ float T[32][33];
  const int n0 = blockIdx.x * 32, k0 = blockIdx.y * 32;
  const int tid = threadIdx.x;
#pragma unroll
  for (int i = 0; i < 4; ++i) {
    int e = i * 256 + tid, r = e >> 5, c = e & 31;
    T[r][c] = W[(size_t)(k0 + r) * N + n0 + c];
  }
  __syncthreads();
#pragma unroll
  for (int i = 0; i < 4; ++i) {
    int e = i * 256 + tid, r = e >> 5, c = e & 31;
    Wt[(size_t)(n0 + r) * K + k0 + c] = f2bf(T[c][r]);
  }
}

// =====================================================================================
// 8-wave GEMM: BM=128, BN=256, BK=64, 3-slot cyclic LDS, counted vmcnt (T3/T4).
// 512 thr = 8 waves (2M x 4N), per-wave 64x64 out, acc[4][4] f32x4.
// LDS 144 KB dynamic: A 3x[128][64] + B 3x[256][64] bf16. Slot for K-tile t = t%3.
// Per K-tile: sched_fence -> s_waitcnt vmcnt(6) -> s_barrier -> STAGE(t+2 -> slot
// (t+2)%3, 6 gld16/thread) -> 2x{8 ds_read_b128 + setprio(1) 16 MFMA setprio(0)}.
// vmcnt(6): exactly tile t+1's 6 loads stay in flight across the barrier; staged
// 2 bodies before use (covers HBM latency). vmcnt(0) only at last tile.
// Swizzle (validated R4): LDS[row][c] holds global chunk c^(row&7); frag read uses
// chunk ((kk*4+quad)^(l16&7)) -> conflict-free stride-128B ds_read_b128.
// Staging dest is linear (gld16: wave-uniform base + lane*16B); source pre-swizzled:
// lane covers row (lane>>3), global chunk (lane&7)^(lane>>3).
// =====================================================================================
#define KDIM 768
#define NKT  12

#define STG(t_, s_)                                                            \
  do {                                                                         \
    const u16* ga = AgA + (size_t)(t_) * 64;                                   \
    const u16* gb = BgB + (size_t)(t_) * 64;                                   \
    u16* da = Asl + (s_) * 8192 + wave * 1024;                                 \
    u16* db = Bsl + (s_) * 16384 + wave * 2048;                                \
    gld16(ga, da);                 gld16(ga + 8 * KDIM, da + 512);             \
    gld16(gb, db);                 gld16(gb + 8 * KDIM, db + 512);             \
    gld16(gb + 16 * KDIM, db + 1024); gld16(gb + 24 * KDIM, db + 1536);        \
  } while (0)

#define GEMM3_BODY(A_, Bt_)                                                    \
  extern __shared__ u16 smem[];                                                \
  u16* Asl = smem;                /* 3 x 8192  u16 */                          \
  u16* Bsl = smem + 3 * 8192;     /* 3 x 16384 u16 */                          \
  const int tid = threadIdx.x;                                                 \
  const int wave = tid >> 6, lane = tid & 63;                                  \
  const int quad = lane >> 4, l16 = lane & 15;                                 \
  const int wm = wave >> 2, wn = wave & 3;                                     \
  const int m0 = blockIdx.y * 128, n0 = blockIdx.x * 256;                      \
  const int srow = lane >> 3;                                                  \
  const int sch = (lane & 7) ^ srow;                                           \
  const u16* AgA = (A_) + (size_t)(m0 + wave * 16 + srow) * KDIM + sch * 8;    \
  const u16* BgB = (Bt_) + (size_t)(n0 + wave * 32 + srow) * KDIM + sch * 8;   \
  f32x4 acc[4][4];                                                             \
  _Pragma("unroll")                                                            \
  for (int i = 0; i < 4; ++i)                                                  \
    _Pragma("unroll")                                                          \
    for (int j = 0; j < 4; ++j) acc[i][j] = (f32x4){0.f, 0.f, 0.f, 0.f};       \
  STG(0, 0);                                                                   \
  STG(1, 1);                                                                   \
  for (int t = 0; t < NKT; ++t) {                                              \
    __builtin_amdgcn_sched_barrier(0);                                         \
    if (t < NKT - 1) asm volatile("s_waitcnt vmcnt(6)" ::: "memory");          \
    else             asm volatile("s_waitcnt vmcnt(0)" ::: "memory");          \
    __builtin_amdgcn_sched_barrier(0);                                         \
    __builtin_amdgcn_s_barrier();                                              \
    __builtin_amdgcn_sched_barrier(0);                                         \
    if (t + 2 < NKT) STG(t + 2, (t + 2) % 3);                                  \
    const u16* Ab = Asl + (t % 3) * 8192 + (wm * 64 + l16) * 64;               \
    const u16* Bb = Bsl + (t % 3) * 16384 + (wn * 64 + l16) * 64;              \
    _Pragma("unroll")                                                          \
    for (int kk = 0; kk < 2; ++kk) {                                           \
      const int co = (((kk << 2) | quad) ^ (l16 & 7)) << 3;                    \
      bf16x8 af[4], bfr[4];                                                    \
      _Pragma("unroll")                                                        \
      for (int rb = 0; rb < 4; ++rb) af[rb] = ldfrag(Ab + rb * 1024 + co);     \
      _Pragma("unroll")                                                        \
      for (int cb = 0; cb < 4; ++cb) bfr[cb] = ldfrag(Bb + cb * 1024 + co);    \
      __builtin_amdgcn_s_setprio(1);                                           \
      _Pragma("unroll")                                                        \
      for (int rb = 0; rb < 4; ++rb)                                           \
        _Pragma("unroll")                                                      \
        for (int cb = 0; cb < 4; ++cb)                                         \
          acc[rb][cb] = __builtin_amdgcn_mfma_f32_16x16x32_bf16(               \
              af[rb], bfr[cb], acc[rb][cb], 0, 0, 0);                          \
      __builtin_amdgcn_s_setprio(0);                                           \
    }                                                                          \
  }

// ---------------- proj GEMM: C[M,N] = A[M,K] * Bt[N,K]^T + bias (f32 out) -----------
__global__ __launch_bounds__(512, 2)
void gemm_bt(const u16* __restrict__ A, const u16* __restrict__ Bt,
             const float* __restrict__ bias, float* __restrict__ C,
             int M, int N, int Karg) {
  (void)M; (void)Karg;
  GEMM3_BODY(A, Bt)
#pragma unroll
  for (int cb = 0; cb < 4; ++cb) {
    int col = n0 + wn * 64 + cb * 16 + l16;
    float bv = bias[col];
#pragma unroll
    for (int rb = 0; rb < 4; ++rb) {
#pragma unroll
      for (int r = 0; r < 4; ++r) {
        int row = m0 + wm * 64 + rb * 16 + quad * 4 + r;
        C[(size_t)row * N + col] = acc[rb][cb][r] + bv;
      }
    }
  }
}

// ---------------- fused QKV GEMM + bias + RoPE + scatter ----------------------------
// Grid (9, 64): blockIdx.x 0-2 Q, 3-5 K, 6-8 V (256 | 768). Wave col-span 64 == one
// head (wn*64). RoPE pair (d, d+32) lives in acc blocks (cb, cb+2) of the SAME lane.
// Q gets D^-0.5*log2e folded in (attn softmax runs in log2 domain).
// Q,K -> (B*H, N, D) bf16; V -> transposed (B*H, D, N) bf16 (4 tokens per 8B store).
__global__ __launch_bounds__(512, 2)
void gemm_qkv_rope(const u16* __restrict__ A, const u16* __restrict__ Bt,
                   const float* __restrict__ bias,
                   const float* __restrict__ cosT, const float* __restrict__ sinT,
                   const int* __restrict__ nsp,
                   u16* __restrict__ Qo, u16* __restrict__ Ko, u16* __restrict__ Vto) {
  GEMM3_BODY(A, Bt)
  // ---- fused epilogue ----
  const int gcol0 = n0 + wn * 64;          // global col of this wave's head
  const int sec = gcol0 / 768;             // 0=Q, 1=K, 2=V
  const int hh = (gcol0 >> 6) % 12;
  const int bb = m0 >> 11;                 // 2048 % 128 == 0: one batch per block
  const int nbase = m0 & 2047;
  const int bh = bb * 12 + hh;
  const int num_special = nsp[0];
  const float QS = 0.125f * 1.4426950408889634f;  // D^-0.5 * log2e
  const int gc64 = gcol0 % 768;            // head-base within section (unused)
  (void)gc64;

  if (sec < 2) {
    u16* outp = sec ? Ko : Qo;
    const float qs = sec ? 1.0f : QS;
#pragma unroll
    for (int cbp = 0; cbp < 2; ++cbp) {
      const int d1 = cbp * 16 + l16;       // 0..31
      const int d2 = d1 + 32;
      const float bv1 = bias[gcol0 + d1];
      const float bv2 = bias[gcol0 + d2];
#pragma unroll
      for (int rb = 0; rb < 4; ++rb) {
#pragma unroll
        for (int r = 0; r < 4; ++r) {
          const int n = nbase + wm * 64 + rb * 16 + quad * 4 + r;
          float v1 = acc[rb][cbp][r] + bv1;
          float v2 = acc[rb][cbp + 2][r] + bv2;
          float o1, o2;
          if (n < num_special) {
            o1 = v1; o2 = v2;
          } else {
            int ns = n - num_special;
            float c1 = cosT[ns * 64 + d1], s1 = sinT[ns * 64 + d1];
            float c2 = cosT[ns * 64 + d2], s2 = sinT[ns * 64 + d2];
            o1 = v1 * c1 - v2 * s1;
            o2 = v2 * c2 + v1 * s2;
          }
          size_t ob = ((size_t)bh * 2048 + n) * 64;
          outp[ob + d1] = f2bf(o1 * qs);
          outp[ob + d2] = f2bf(o2 * qs);
        }
      }
    }
  } else {
    // V: bias + transposed write (d-major), 4 consecutive tokens per 8B store
#pragma unroll
    for (int cb = 0; cb < 4; ++cb) {
      const int d = cb * 16 + l16;
      const float bv = bias[gcol0 + d];
#pragma unroll
      for (int rb = 0; rb < 4; ++rb) {
        const int nr = nbase + wm * 64 + rb * 16 + quad * 4;
        U64v o;
        o.x = (uint32_t)f2bf(acc[rb][cb][0] + bv) |
              ((uint32_t)f2bf(acc[rb][cb][1] + bv) << 16);
        o.y = (uint32_t)f2bf(acc[rb][cb][2] + bv) |
              ((uint32_t)f2bf(acc[rb][cb][3] + bv) << 16);
        *(U64v*)&Vto[((size_t)bh * 64 + d) * 2048 + nr] = o;
      }
    }
  }
}

// ---------------- flash attention: wave-owns-keys, T15 att[2] software pipeline ----
// SPLIT into two 768-block launches (qt0 = 0, 16): 3 blocks/CU x 256 CUs full
// residency per launch. Per-launch grid 768 = qtl*48 + bh.
// 4 waves; wave owns keys [wave*16, wave*16+16) of each 64-key tile. Q hoisted to
// registers. K/V staged via global_load_lds width-16 (linear dest + XOR swizzle).
// PIPELINE (T15): body kt computes {QK^T + exp of tile kt+1} braided with {PV of kt}.
// S^T = MFMA(A=K_own, B=Q); exp'd values are directly the PV A-frag. No-max softmax.
__global__ __launch_bounds__(256, 3)
void attn(const u16* __restrict__ Q, const u16* __restrict__ Kg,
          const u16* __restrict__ Vt, u16* __restrict__ Out, int qt0) {
  __shared__ u16 smem2[2 * 8192];    // 32 KB: [buf][K 64x64 | V 64x64]; epilogue OR overlays
  __shared__ float invS[64];
  const int tid = threadIdx.x;
  const int wave = tid >> 6, lane = tid & 63;
  const int quad = lane >> 4, l16 = lane & 15;
  const int idx = blockIdx.x;
  const int bh = idx % 48, qt = idx / 48 + qt0;
  const int b = bh / 12, h = bh % 12;
  const u16* Qb = Q + (size_t)bh * 2048 * 64;
  const u16* Kb = Kg + (size_t)bh * 2048 * 64;
  const u16* Vb = Vt + (size_t)bh * 64 * 2048;
  const int wkey0 = wave * 16;

  // ---- staging geometry (loop-invariant) ----
  const int lrow = lane >> 3;                 // 0..7 within an 8-row call region
  const int lch  = (lane & 7) ^ (lrow & 7);   // pre-swizzled source 16B-chunk
  const int r0a = wave * 8;                   // call 0 rows
  const int r0b = 32 + wave * 8;              // call 1 rows
  const int ksrc_a = (r0a + lrow) * 64 + lch * 8;   // u16 offsets into a [64][64] K tile
  const int ksrc_b = (r0b + lrow) * 64 + lch * 8;
  const size_t vsrc_a = (size_t)(r0a + lrow) * 2048 + lch * 8;  // V rows are d-rows
  const size_t vsrc_b = (size_t)(r0b + lrow) * 2048 + lch * 8;

  // ---- LDS read offsets (swizzled, loop-invariant) ----
  const int krd = (wkey0 + l16) * 64 + ((quad ^ (l16 & 7)) << 3);     // ka0; ka1 = ^32
  int vrd[4];
#pragma unroll
  for (int db = 0; db < 4; ++db)
    vrd[db] = (db * 16 + l16) * 64 +
              ((((wave << 1) | (quad >> 1)) ^ (l16 & 7)) << 3) + (quad & 1) * 4;

#define STAGE_A(kt_, s_)                                                      \
  do {                                                                        \
    u16* Kd = smem2 + (s_) * 8192;                                            \
    u16* Vd = Kd + 4096;                                                      \
    const u16* Ksrc = Kb + (size_t)(kt_) * 4096;                              \
    const u16* Vsrc = Vb + (kt_) * 64;                                        \
    gld16(Ksrc + ksrc_a, Kd + r0a * 64);                                      \
    gld16(Ksrc + ksrc_b, Kd + r0b * 64);                                      \
    gld16(Vsrc + vsrc_a, Vd + r0a * 64);                                      \
    gld16(Vsrc + vsrc_b, Vd + r0b * 64);                                      \
  } while (0)

  // Q fragments: direct global load (one-time; reused 32x)
  bf16x8 qf[4][2];
#pragma unroll
  for (int m = 0; m < 4; ++m) {
    const u16* qp = Qb + (size_t)(qt * 64 + m * 16 + l16) * 64 + quad * 8;
    qf[m][0] = ldfrag(qp);
    qf[m][1] = ldfrag(qp + 32);
  }

  f32x4 oacc[4][4];  // [q-block m][d-block db], partial over this wave's keys
#pragma unroll
  for (int m = 0; m < 4; ++m)
#pragma unroll
    for (int db = 0; db < 4; ++db) oacc[m][db] = (f32x4){0.f, 0.f, 0.f, 0.f};
  float psum[4] = {0.f, 0.f, 0.f, 0.f};

  // ---- prologue: stage tiles 0 and 1; QK+exp of tile 0 ----
  STAGE_A(0, 0);
  STAGE_A(1, 1);
  __syncthreads();                        // both buffers staged

  s16x4 pf[4];
  U64v  vfc[4];
  {
    const u16* Ksh = smem2;
    const u16* Vsh = smem2 + 4096;
    bf16x8 ka0 = ldfrag(Ksh + krd);
    bf16x8 ka1 = ldfrag(Ksh + (krd ^ 32));
#pragma unroll
    for (int db = 0; db < 4; ++db) vfc[db] = *(const U64v*)(Vsh + vrd[db]);
#pragma unroll
    for (int m = 0; m < 4; ++m) {
      f32x4 st = (f32x4){0.f, 0.f, 0.f, 0.f};
      st = __builtin_amdgcn_mfma_f32_16x16x32_bf16(ka0, qf[m][0], st, 0, 0, 0);
      st = __builtin_amdgcn_mfma_f32_16x16x32_bf16(ka1, qf[m][1], st, 0, 0, 0);
      float p0 = EXP2(st[0]), p1 = EXP2(st[1]), p2 = EXP2(st[2]), p3 = EXP2(st[3]);
      psum[m] += (p0 + p1) + (p2 + p3);
      U64v pd; pd.x = pkbf(p0, p1); pd.y = pkbf(p2, p3);
      pf[m] = __builtin_bit_cast(s16x4, pd);
    }
  }
  __syncthreads();                        // all waves done reading buf0 (body 0 restages it)

  // ---- steady state: QK/exp(kt+1) braided with PV(kt) ----
  for (int kt = 0; kt < 31; ++kt) {
    const int cur = kt & 1, nxt = cur ^ 1;
    const u16* Kshn = smem2 + nxt * 8192;
    const u16* Vshn = Kshn + 4096;
    bf16x8 kn0 = ldfrag(Kshn + krd);
    bf16x8 kn1 = ldfrag(Kshn + (krd ^ 32));
    U64v vfn[4];
#pragma unroll
    for (int db = 0; db < 4; ++db) vfn[db] = *(const U64v*)(Vshn + vrd[db]);

    if (kt < 30) STAGE_A(kt + 2, cur);    // overwrite tile-kt buffer (reads done last body)

    s16x4 pfn[4];
#pragma unroll
    for (int m = 0; m < 4; ++m) {
      // QK stream (tile kt+1)
      f32x4 st = (f32x4){0.f, 0.f, 0.f, 0.f};
      st = __builtin_amdgcn_mfma_f32_16x16x32_bf16(kn0, qf[m][0], st, 0, 0, 0);
      st = __builtin_amdgcn_mfma_f32_16x16x32_bf16(kn1, qf[m][1], st, 0, 0, 0);
      // PV stream (tile kt) — independent, fills MFMA pipe while exp runs on VALU
#pragma unroll
      for (int db = 0; db < 4; ++db)
        oacc[m][db] = __builtin_amdgcn_mfma_f32_16x16x16bf16_1k(pf[m], __builtin_bit_cast(s16x4, vfc[db]), oacc[m][db], 0, 0, 0);
      float p0 = EXP2(st[0]), p1 = EXP2(st[1]), p2 = EXP2(st[2]), p3 = EXP2(st[3]);
      psum[m] += (p0 + p1) + (p2 + p3);
      U64v pd; pd.x = pkbf(p0, p1); pd.y = pkbf(p2, p3);
      pfn[m] = __builtin_bit_cast(s16x4, pd);
    }
    __syncthreads();                      // drains STAGE(kt+2); next body reads buf[cur]
#pragma unroll
    for (int m = 0; m < 4; ++m) pf[m] = pfn[m];
#pragma unroll
    for (int db = 0; db < 4; ++db) vfc[db] = vfn[db];
  }

  // ---- drain: PV of tile 31 ----
#pragma unroll
  for (int m = 0; m < 4; ++m)
#pragma unroll
    for (int db = 0; db < 4; ++db)
      oacc[m][db] = __builtin_amdgcn_mfma_f32_16x16x16bf16_1k(pf[m], __builtin_bit_cast(s16x4, vfc[db]), oacc[m][db], 0, 0, 0);
#undef STAGE_A

  // ---- epilogue: cross-wave reductions ----
#pragma unroll
  for (int m = 0; m < 4; ++m) {
    psum[m] += __shfl_xor(psum[m], 16, 64);
    psum[m] += __shfl_xor(psum[m], 32, 64);
  }
  __syncthreads();
  float* LS = (float*)smem2;       // [wave][64 q]
  if (quad == 0) {
#pragma unroll
    for (int m = 0; m < 4; ++m) LS[wave * 64 + m * 16 + l16] = psum[m];
  }
  __syncthreads();
  if (tid < 64) {
    float tot = LS[tid] + LS[64 + tid] + LS[128 + tid] + LS[192 + tid];
    invS[tid] = 1.0f / tot;
  }

  float* OR = (float*)smem2;       // 4*64*18*4 B = 18432 B < 32 KB
  const int q = tid >> 2;
  const int d0 = (tid & 3) * 4;
  const size_t obase = ((size_t)(b * 2048 + qt * 64 + q)) * 768 + h * 64 + d0;
#pragma unroll
  for (int db = 0; db < 4; ++db) {
    __syncthreads();
#pragma unroll
    for (int m = 0; m < 4; ++m)
#pragma unroll
      for (int r = 0; r < 4; ++r)
        OR[(wave * 64 + m * 16 + quad * 4 + r) * 18 + l16] = oacc[m][db][r];
    __syncthreads();
    float s0 = 0.f, s1 = 0.f, s2 = 0.f, s3 = 0.f;
#pragma unroll
    for (int w = 0; w < 4; ++w) {
      const float* p = &OR[(w * 64 + q) * 18 + d0];
      s0 += p[0]; s1 += p[1]; s2 += p[2]; s3 += p[3];
    }
    float iv = invS[q];
    U64v o;
    o.x = (uint32_t)f2bf(s0 * iv) | ((uint32_t)f2bf(s1 * iv) << 16);
    o.y = (uint32_t)f2bf(s2 * iv) | ((uint32_t)f2bf(s3 * iv) << 16);
    *(U64v*)&Out[obase + db * 16] = o;
  }
}

extern "C" void kernel_launch(void* const* d_in, const int* in_sizes, int n_in,
                              void* d_out, int out_size, void* d_ws, size_t ws_size,
                              hipStream_t stream) {
  (void)in_sizes; (void)n_in; (void)out_size; (void)ws_size;
  const float* x        = (const float*)d_in[0];
  const float* rope_cos = (const float*)d_in[1];
  const float* rope_sin = (const float*)d_in[2];
  const float* W_qkv    = (const float*)d_in[3];
  const float* b_qkv    = (const float*)d_in[4];
  const float* W_proj   = (const float*)d_in[5];
  const float* b_proj   = (const float*)d_in[6];
  const int*   nsp      = (const int*)d_in[7];
  float* out = (float*)d_out;

  char* ws = (char*)d_ws;
  u16* Xb   = (u16*)(ws);              // 8192x768 bf16
  u16* Wqkt = (u16*)(ws + 12582912);   // 2304x768 bf16
  u16* Wpt  = (u16*)(ws + 16121856);   // 768x768 bf16
  u16* Qb   = (u16*)(ws + 55050240);   // 48x2048x64 bf16
  u16* Kb   = (u16*)(ws + 67633152);
  u16* Vtb  = (u16*)(ws + 80216064);   // 48x64x2048 bf16
  u16* att  = (u16*)(ws + 92798976);   // 8192x768 bf16

  static bool attr_done = false;
  if (!attr_done) {
    hipFuncSetAttribute(reinterpret_cast<const void*>(gemm_qkv_rope),
                        hipFuncAttributeMaxDynamicSharedMemorySize, 147456);
    hipFuncSetAttribute(reinterpret_cast<const void*>(gemm_bt),
                        hipFuncAttributeMaxDynamicSharedMemorySize, 147456);
    attr_done = true;
  }

  cvt_f32_bf16<<<6144, 256, 0, stream>>>(x, Xb);
  transpose_cvt<<<dim3(72, 24), 256, 0, stream>>>(W_qkv, Wqkt, 768, 2304);
  transpose_cvt<<<dim3(24, 24), 256, 0, stream>>>(W_proj, Wpt, 768, 768);
  gemm_qkv_rope<<<dim3(9, 64), 512, 147456, stream>>>(Xb, Wqkt, b_qkv, rope_cos, rope_sin,
                                                      nsp, Qb, Kb, Vtb);
  attn<<<768, 256, 0, stream>>>(Qb, Kb, Vtb, att, 0);
  attn<<<768, 256, 0, stream>>>(Qb, Kb, Vtb, att, 16);
  gemm_bt<<<dim3(3, 64), 512, 147456, stream>>>(att, Wpt, b_proj, out, 8192, 768, 768);
}

// Round 7
// 248.875 us; speedup vs baseline: 1.0576x; 1.0576x over previous
//
#include <hip/hip_runtime.h>
#include <stdint.h>

typedef unsigned short u16;
typedef __bf16 bf16x8 __attribute__((ext_vector_type(8)));
typedef __bf16 bf16x2 __attribute__((ext_vector_type(2)));
typedef short s16x4 __attribute__((ext_vector_type(4)));
typedef float f32x4 __attribute__((ext_vector_type(4)));

typedef __attribute__((address_space(1))) void gvoid_t;
typedef __attribute__((address_space(3))) void lvoid_t;

struct alignas(16) U128 { uint32_t x, y, z, w; };
struct alignas(16) F128 { float x, y, z, w; };
struct alignas(8)  U64v { uint32_t x, y; };

__device__ __forceinline__ void gld16(const u16* g, u16* lds) {
  __builtin_amdgcn_global_load_lds((gvoid_t*)const_cast<u16*>(g),
                                   (lvoid_t*)lds, 16, 0, 0);
}

__device__ __forceinline__ u16 f2bf(float f) {
  uint32_t u = __builtin_bit_cast(uint32_t, f);
  u += 0x7FFFu + ((u >> 16) & 1u);   // RNE
  return (u16)(u >> 16);
}
__device__ __forceinline__ float bf2f(u16 h) {
  return __builtin_bit_cast(float, (uint32_t)h << 16);
}
__device__ __forceinline__ bf16x8 ldfrag(const u16* p) {
  U128 u = *reinterpret_cast<const U128*>(p);
  return __builtin_bit_cast(bf16x8, u);
}
// pack two f32 -> bf16x2 dword via HW cvt (compiler emits v_cvt_pk_bf16_f32)
__device__ __forceinline__ uint32_t pkbf(float a, float b) {
  bf16x2 v;
  v[0] = (__bf16)a;
  v[1] = (__bf16)b;
  return __builtin_bit_cast(uint32_t, v);
}

// raw v_exp_f32 (exp2) — scores bounded (|s|<~10), no denormal concerns
__device__ __forceinline__ float EXP2(float x) { return __builtin_amdgcn_exp2f(x); }

// ---------------- fp32 -> bf16 convert (x) ----------------
__global__ void cvt_f32_bf16(const float* __restrict__ in, u16* __restrict__ out) {
  int i = (blockIdx.x * 256 + threadIdx.x) * 4;
  F128 v = *reinterpret_cast<const F128*>(in + i);
  U64v o;
  o.x = (uint32_t)f2bf(v.x) | ((uint32_t)f2bf(v.y) << 16);
  o.y = (uint32_t)f2bf(v.z) | ((uint32_t)f2bf(v.w) << 16);
  *reinterpret_cast<U64v*>(out + i) = o;
}

// ---------------- transpose + convert weights: W (K x N f32) -> Wt (N x K bf16) ----
__global__ void transpose_cvt(const float* __restrict__ W, u16* __restrict__ Wt,
                              int K, int N) {
  __shared__ float T[32][33];
  const int n0 = blockIdx.x * 32, k0 = blockIdx.y * 32;
  const int tid = threadIdx.x;
#pragma unroll
  for (int i = 0; i < 4; ++i) {
    int e = i * 256 + tid, r = e >> 5, c = e & 31;
    T[r][c] = W[(size_t)(k0 + r) * N + n0 + c];
  }
  __syncthreads();
#pragma unroll
  for (int i = 0; i < 4; ++i) {
    int e = i * 256 + tid, r = e >> 5, c = e & 31;
    Wt[(size_t)(n0 + r) * K + k0 + c] = f2bf(T[c][r]);
  }
}

// =====================================================================================
// 4-wave GEMM, R5 geometry + T3/T4 pipeline: BM=BN=128, BK=32, 3-slot cyclic LDS
// (48 KB static -> 3 blocks/CU, 12 waves/CU), counted vmcnt.
// Per K-tile t: sched_fence -> s_waitcnt vmcnt(4) [tile t retired, t+1's 4 loads
// stay IN FLIGHT across the barrier] -> s_barrier -> STAGE(t+2 -> slot (t+2)%3)
// -> 8 ds_read_b128 + setprio(1) 16 MFMA setprio(0). vmcnt(0) only at last tile.
// Slot hazard: body t overwrites slot (t-1)%3, whose reads completed last body
// (compiler waits lgkmcnt before MFMA use) and are fenced by this body's barrier.
// LDS rows are 32 u16 = 64B -> wave64 ds_read_b128 is conflict-free by construction
// (R6 measured SQ_LDS_BANK_CONFLICT = 0 on this row width). No swizzle needed.
// XCD swizzle (bijective, grid%8==0): XCD c gets a contiguous chunk of the grid so
// blocks sharing an A-panel land on ONE XCD's L2 (R6 showed 113MB refetch without).
// =====================================================================================

#define GEMM_PIPE(A_, Bt_, KD_, NKT_)                                                \
  const int tid = threadIdx.x;                                                       \
  const int wave = tid >> 6, lane = tid & 63;                                        \
  const int quad = lane >> 4, l16 = lane & 15;                                       \
  const int m0 = by * 128, n0 = bx * 128;                                            \
  const int wr = (wave & 1) * 64, wc = (wave >> 1) * 64;                             \
  f32x4 acc[4][4];                                                                   \
  _Pragma("unroll")                                                                  \
  for (int i = 0; i < 4; ++i)                                                        \
    _Pragma("unroll")                                                                \
    for (int j = 0; j < 4; ++j) acc[i][j] = (f32x4){0.f, 0.f, 0.f, 0.f};             \
  const int c0 = wave * 128 + lane;                                                  \
  const int row0 = c0 >> 2, kq0 = c0 & 3;                                            \
  const int c1 = c0 + 64;                                                            \
  const int row1 = c1 >> 2, kq1 = c1 & 3;                                            \
  const u16* Ag0 = (A_) + (size_t)(m0 + row0) * (KD_) + kq0 * 8;                     \
  const u16* Ag1 = (A_) + (size_t)(m0 + row1) * (KD_) + kq1 * 8;                     \
  const u16* Bg0 = (Bt_) + (size_t)(n0 + row0) * (KD_) + kq0 * 8;                    \
  const u16* Bg1 = (Bt_) + (size_t)(n0 + row1) * (KD_) + kq1 * 8;                    \
  STG(0, 0);                                                                         \
  STG(1, 1);                                                                         \
  for (int t = 0; t < (NKT_); ++t) {                                                 \
    __builtin_amdgcn_sched_barrier(0);                                               \
    if (t < (NKT_) - 1) asm volatile("s_waitcnt vmcnt(4)" ::: "memory");             \
    else                asm volatile("s_waitcnt vmcnt(0)" ::: "memory");             \
    __builtin_amdgcn_sched_barrier(0);                                               \
    __builtin_amdgcn_s_barrier();                                                    \
    __builtin_amdgcn_sched_barrier(0);                                               \
    if (t + 2 < (NKT_)) STG(t + 2, (t + 2) % 3);                                     \
    const u16* Ab = Asl + (t % 3) * 4096;                                            \
    const u16* Bb = Bsl + (t % 3) * 4096;                                            \
    bf16x8 af[4], bfr[4];                                                            \
    _Pragma("unroll")                                                                \
    for (int rb = 0; rb < 4; ++rb)                                                   \
      af[rb] = ldfrag(&Ab[(wr + rb * 16 + l16) * 32 + quad * 8]);                    \
    _Pragma("unroll")                                                                \
    for (int cb = 0; cb < 4; ++cb)                                                   \
      bfr[cb] = ldfrag(&Bb[(wc + cb * 16 + l16) * 32 + quad * 8]);                   \
    __builtin_amdgcn_s_setprio(1);                                                   \
    _Pragma("unroll")                                                                \
    for (int rb = 0; rb < 4; ++rb)                                                   \
      _Pragma("unroll")                                                              \
      for (int cb = 0; cb < 4; ++cb)                                                 \
        acc[rb][cb] = __builtin_amdgcn_mfma_f32_16x16x32_bf16(                       \
            af[rb], bfr[cb], acc[rb][cb], 0, 0, 0);                                  \
    __builtin_amdgcn_s_setprio(0);                                                   \
  }

#define STG(t_, s_)                                                                  \
  do {                                                                               \
    const int k0_ = (t_) * 32;                                                       \
    gld16(Ag0 + k0_, &Asl[(s_) * 4096 + wave * 1024]);                               \
    gld16(Bg0 + k0_, &Bsl[(s_) * 4096 + wave * 1024]);                               \
    gld16(Ag1 + k0_, &Asl[(s_) * 4096 + wave * 1024 + 512]);                         \
    gld16(Bg1 + k0_, &Bsl[(s_) * 4096 + wave * 1024 + 512]);                         \
  } while (0)

// ---------------- proj GEMM: C[M,N] = A[M,K] * Bt[N,K]^T + bias (f32 out) -----------
__global__ __launch_bounds__(256, 3)
void gemm_bt(const u16* __restrict__ A, const u16* __restrict__ Bt,
             const float* __restrict__ bias, float* __restrict__ C,
             int M, int N, int Karg) {
  (void)M; (void)Karg;
  __shared__ u16 Asl[3 * 4096];
  __shared__ u16 Bsl[3 * 4096];
  // XCD swizzle: grid (6,64) = 384 blocks, 48/XCD -> XCD c covers 8 A-panels
  const int orig = blockIdx.y * 6 + blockIdx.x;
  const int swz = (orig % 8) * 48 + orig / 8;
  const int bx = swz % 6, by = swz / 6;
  GEMM_PIPE(A, Bt, 768, 24)
#pragma unroll
  for (int cb = 0; cb < 4; ++cb) {
    int col = n0 + wc + cb * 16 + l16;
    float bv = bias[col];
#pragma unroll
    for (int rb = 0; rb < 4; ++rb) {
#pragma unroll
      for (int r = 0; r < 4; ++r) {
        int row = m0 + wr + rb * 16 + quad * 4 + r;
        C[(size_t)row * N + col] = acc[rb][cb][r] + bv;
      }
    }
  }
}

// ---------------- fused QKV GEMM + bias + RoPE + scatter ----------------------------
// Grid (18,64), XCD-swizzled. bx: 0-5 Q, 6-11 K, 12-17 V. Wave col-span 64 == one
// head. RoPE pair (d, d+32) lives in acc blocks (cb, cb+2) of the SAME lane.
// Q gets D^-0.5*log2e folded in (attn softmax runs in log2 domain).
// Q,K -> (B*H, N, D) bf16; V -> transposed (B*H, D, N) bf16 (4 tokens per 8B store).
__global__ __launch_bounds__(256, 3)
void gemm_qkv_rope(const u16* __restrict__ A, const u16* __restrict__ Bt,
                   const float* __restrict__ bias,
                   const float* __restrict__ cosT, const float* __restrict__ sinT,
                   const int* __restrict__ nsp,
                   u16* __restrict__ Qo, u16* __restrict__ Ko, u16* __restrict__ Vto) {
  __shared__ u16 Asl[3 * 4096];
  __shared__ u16 Bsl[3 * 4096];
  // XCD swizzle: grid (18,64) = 1152 blocks, 144/XCD -> XCD c covers 8 A-panels
  const int orig = blockIdx.y * 18 + blockIdx.x;
  const int swz = (orig % 8) * 144 + orig / 8;
  const int bx = swz % 18, by = swz / 18;
  GEMM_PIPE(A, Bt, 768, 24)

  // ---- fused epilogue ----
  const int sec = bx / 6;                  // 0=Q, 1=K, 2=V
  const int gcol0 = n0 + wc;               // 64-aligned: one head per wave
  const int hh = (gcol0 >> 6) % 12;
  const int bb = m0 >> 11;                 // 2048 % 128 == 0: one batch per block
  const int nbase = m0 & 2047;
  const int bh = bb * 12 + hh;
  const int num_special = nsp[0];
  const float QS = 0.125f * 1.4426950408889634f;  // D^-0.5 * log2e

  if (sec < 2) {
    u16* outp = sec ? Ko : Qo;
    const float qs = sec ? 1.0f : QS;
#pragma unroll
    for (int cbp = 0; cbp < 2; ++cbp) {
      const int d1 = cbp * 16 + l16;       // 0..31
      const int d2 = d1 + 32;
      const float bv1 = bias[gcol0 + d1];
      const float bv2 = bias[gcol0 + d2];
#pragma unroll
      for (int rb = 0; rb < 4; ++rb) {
#pragma unroll
        for (int r = 0; r < 4; ++r) {
          const int n = nbase + wr + rb * 16 + quad * 4 + r;
          float v1 = acc[rb][cbp][r] + bv1;
          float v2 = acc[rb][cbp + 2][r] + bv2;
          float o1, o2;
          if (n < num_special) {
            o1 = v1; o2 = v2;
          } else {
            int ns = n - num_special;
            float c1 = cosT[ns * 64 + d1], s1 = sinT[ns * 64 + d1];
            float c2 = cosT[ns * 64 + d2], s2 = sinT[ns * 64 + d2];
            o1 = v1 * c1 - v2 * s1;
            o2 = v2 * c2 + v1 * s2;
          }
          size_t ob = ((size_t)bh * 2048 + n) * 64;
          outp[ob + d1] = f2bf(o1 * qs);
          outp[ob + d2] = f2bf(o2 * qs);
        }
      }
    }
  } else {
    // V: bias + transposed write (d-major), 4 consecutive tokens per 8B store
#pragma unroll
    for (int cb = 0; cb < 4; ++cb) {
      const int d = cb * 16 + l16;
      const float bv = bias[gcol0 + d];
#pragma unroll
      for (int rb = 0; rb < 4; ++rb) {
        const int nr = nbase + wr + rb * 16 + quad * 4;
        U64v o;
        o.x = (uint32_t)f2bf(acc[rb][cb][0] + bv) |
              ((uint32_t)f2bf(acc[rb][cb][1] + bv) << 16);
        o.y = (uint32_t)f2bf(acc[rb][cb][2] + bv) |
              ((uint32_t)f2bf(acc[rb][cb][3] + bv) << 16);
        *(U64v*)&Vto[((size_t)bh * 64 + d) * 2048 + nr] = o;
      }
    }
  }
}

// ---------------- flash attention: wave-owns-keys, T15 att[2] software pipeline ----
// SPLIT into two 768-block launches (qt0 = 0, 16): 3 blocks/CU x 256 CUs full
// residency per launch (keeps GEMM dispatches visible in profiler top-5).
// 4 waves; wave owns keys [wave*16, wave*16+16) of each 64-key tile. Q hoisted to
// registers. K/V staged via global_load_lds width-16 (linear dest + XOR swizzle).
// PIPELINE (T15): body kt computes {QK^T + exp of tile kt+1} braided with {PV of kt}.
// S^T = MFMA(A=K_own, B=Q); exp'd values are directly the PV A-frag. No-max softmax.
__global__ __launch_bounds__(256, 3)
void attn(const u16* __restrict__ Q, const u16* __restrict__ Kg,
          const u16* __restrict__ Vt, u16* __restrict__ Out, int qt0) {
  __shared__ u16 smem2[2 * 8192];    // 32 KB: [buf][K 64x64 | V 64x64]; epilogue OR overlays
  __shared__ float invS[64];
  const int tid = threadIdx.x;
  const int wave = tid >> 6, lane = tid & 63;
  const int quad = lane >> 4, l16 = lane & 15;
  const int idx = blockIdx.x;
  const int bh = idx % 48, qt = idx / 48 + qt0;
  const int b = bh / 12, h = bh % 12;
  const u16* Qb = Q + (size_t)bh * 2048 * 64;
  const u16* Kb = Kg + (size_t)bh * 2048 * 64;
  const u16* Vb = Vt + (size_t)bh * 64 * 2048;
  const int wkey0 = wave * 16;

  // ---- staging geometry (loop-invariant) ----
  const int lrow = lane >> 3;                 // 0..7 within an 8-row call region
  const int lch  = (lane & 7) ^ (lrow & 7);   // pre-swizzled source 16B-chunk
  const int r0a = wave * 8;                   // call 0 rows
  const int r0b = 32 + wave * 8;              // call 1 rows
  const int ksrc_a = (r0a + lrow) * 64 + lch * 8;   // u16 offsets into a [64][64] K tile
  const int ksrc_b = (r0b + lrow) * 64 + lch * 8;
  const size_t vsrc_a = (size_t)(r0a + lrow) * 2048 + lch * 8;  // V rows are d-rows
  const size_t vsrc_b = (size_t)(r0b + lrow) * 2048 + lch * 8;

  // ---- LDS read offsets (swizzled, loop-invariant) ----
  const int krd = (wkey0 + l16) * 64 + ((quad ^ (l16 & 7)) << 3);     // ka0; ka1 = ^32
  int vrd[4];
#pragma unroll
  for (int db = 0; db < 4; ++db)
    vrd[db] = (db * 16 + l16) * 64 +
              ((((wave << 1) | (quad >> 1)) ^ (l16 & 7)) << 3) + (quad & 1) * 4;

#define STAGE_A(kt_, s_)                                                      \
  do {                                                                        \
    u16* Kd = smem2 + (s_) * 8192;                                            \
    u16* Vd = Kd + 4096;                                                      \
    const u16* Ksrc = Kb + (size_t)(kt_) * 4096;                              \
    const u16* Vsrc = Vb + (kt_) * 64;                                        \
    gld16(Ksrc + ksrc_a, Kd + r0a * 64);                                      \
    gld16(Ksrc + ksrc_b, Kd + r0b * 64);                                      \
    gld16(Vsrc + vsrc_a, Vd + r0a * 64);                                      \
    gld16(Vsrc + vsrc_b, Vd + r0b * 64);                                      \
  } while (0)

  // Q fragments: direct global load (one-time; reused 32x)
  bf16x8 qf[4][2];
#pragma unroll
  for (int m = 0; m < 4; ++m) {
    const u16* qp = Qb + (size_t)(qt * 64 + m * 16 + l16) * 64 + quad * 8;
    qf[m][0] = ldfrag(qp);
    qf[m][1] = ldfrag(qp + 32);
  }

  f32x4 oacc[4][4];  // [q-block m][d-block db], partial over this wave's keys
#pragma unroll
  for (int m = 0; m < 4; ++m)
#pragma unroll
    for (int db = 0; db < 4; ++db) oacc[m][db] = (f32x4){0.f, 0.f, 0.f, 0.f};
  float psum[4] = {0.f, 0.f, 0.f, 0.f};

  // ---- prologue: stage tiles 0 and 1; QK+exp of tile 0 ----
  STAGE_A(0, 0);
  STAGE_A(1, 1);
  __syncthreads();                        // both buffers staged

  s16x4 pf[4];
  U64v  vfc[4];
  {
    const u16* Ksh = smem2;
    const u16* Vsh = smem2 + 4096;
    bf16x8 ka0 = ldfrag(Ksh + krd);
    bf16x8 ka1 = ldfrag(Ksh + (krd ^ 32));
#pragma unroll
    for (int db = 0; db < 4; ++db) vfc[db] = *(const U64v*)(Vsh + vrd[db]);
#pragma unroll
    for (int m = 0; m < 4; ++m) {
      f32x4 st = (f32x4){0.f, 0.f, 0.f, 0.f};
      st = __builtin_amdgcn_mfma_f32_16x16x32_bf16(ka0, qf[m][0], st, 0, 0, 0);
      st = __builtin_amdgcn_mfma_f32_16x16x32_bf16(ka1, qf[m][1], st, 0, 0, 0);
      float p0 = EXP2(st[0]), p1 = EXP2(st[1]), p2 = EXP2(st[2]), p3 = EXP2(st[3]);
      psum[m] += (p0 + p1) + (p2 + p3);
      U64v pd; pd.x = pkbf(p0, p1); pd.y = pkbf(p2, p3);
      pf[m] = __builtin_bit_cast(s16x4, pd);
    }
  }
  __syncthreads();                        // all waves done reading buf0 (body 0 restages it)

  // ---- steady state: QK/exp(kt+1) braided with PV(kt) ----
  for (int kt = 0; kt < 31; ++kt) {
    const int cur = kt & 1, nxt = cur ^ 1;
    const u16* Kshn = smem2 + nxt * 8192;
    const u16* Vshn = Kshn + 4096;
    bf16x8 kn0 = ldfrag(Kshn + krd);
    bf16x8 kn1 = ldfrag(Kshn + (krd ^ 32));
    U64v vfn[4];
#pragma unroll
    for (int db = 0; db < 4; ++db) vfn[db] = *(const U64v*)(Vshn + vrd[db]);

    if (kt < 30) STAGE_A(kt + 2, cur);    // overwrite tile-kt buffer (reads done last body)

    s16x4 pfn[4];
#pragma unroll
    for (int m = 0; m < 4; ++m) {
      // QK stream (tile kt+1)
      f32x4 st = (f32x4){0.f, 0.f, 0.f, 0.f};
      st = __builtin_amdgcn_mfma_f32_16x16x32_bf16(kn0, qf[m][0], st, 0, 0, 0);
      st = __builtin_amdgcn_mfma_f32_16x16x32_bf16(kn1, qf[m][1], st, 0, 0, 0);
      // PV stream (tile kt) — independent, fills MFMA pipe while exp runs on VALU
#pragma unroll
      for (int db = 0; db < 4; ++db)
        oacc[m][db] = __builtin_amdgcn_mfma_f32_16x16x16bf16_1k(pf[m], __builtin_bit_cast(s16x4, vfc[db]), oacc[m][db], 0, 0, 0);
      float p0 = EXP2(st[0]), p1 = EXP2(st[1]), p2 = EXP2(st[2]), p3 = EXP2(st[3]);
      psum[m] += (p0 + p1) + (p2 + p3);
      U64v pd; pd.x = pkbf(p0, p1); pd.y = pkbf(p2, p3);
      pfn[m] = __builtin_bit_cast(s16x4, pd);
    }
    __syncthreads();                      // drains STAGE(kt+2); next body reads buf[cur]
#pragma unroll
    for (int m = 0; m < 4; ++m) pf[m] = pfn[m];
#pragma unroll
    for (int db = 0; db < 4; ++db) vfc[db] = vfn[db];
  }

  // ---- drain: PV of tile 31 ----
#pragma unroll
  for (int m = 0; m < 4; ++m)
#pragma unroll
    for (int db = 0; db < 4; ++db)
      oacc[m][db] = __builtin_amdgcn_mfma_f32_16x16x16bf16_1k(pf[m], __builtin_bit_cast(s16x4, vfc[db]), oacc[m][db], 0, 0, 0);
#undef STAGE_A

  // ---- epilogue: cross-wave reductions ----
#pragma unroll
  for (int m = 0; m < 4; ++m) {
    psum[m] += __shfl_xor(psum[m], 16, 64);
    psum[m] += __shfl_xor(psum[m], 32, 64);
  }
  __syncthreads();
  float* LS = (float*)smem2;       // [wave][64 q]
  if (quad == 0) {
#pragma unroll
    for (int m = 0; m < 4; ++m) LS[wave * 64 + m * 16 + l16] = psum[m];
  }
  __syncthreads();
  if (tid < 64) {
    float tot = LS[tid] + LS[64 + tid] + LS[128 + tid] + LS[192 + tid];
    invS[tid] = 1.0f / tot;
  }

  float* OR = (float*)smem2;       // 4*64*18*4 B = 18432 B < 32 KB
  const int q = tid >> 2;
  const int d0 = (tid & 3) * 4;
  const size_t obase = ((size_t)(b * 2048 + qt * 64 + q)) * 768 + h * 64 + d0;
#pragma unroll
  for (int db = 0; db < 4; ++db) {
    __syncthreads();
#pragma unroll
    for (int m = 0; m < 4; ++m)
#pragma unroll
      for (int r = 0; r < 4; ++r)
        OR[(wave * 64 + m * 16 + quad * 4 + r) * 18 + l16] = oacc[m][db][r];
    __syncthreads();
    float s0 = 0.f, s1 = 0.f, s2 = 0.f, s3 = 0.f;
#pragma unroll
    for (int w = 0; w < 4; ++w) {
      const float* p = &OR[(w * 64 + q) * 18 + d0];
      s0 += p[0]; s1 += p[1]; s2 += p[2]; s3 += p[3];
    }
    float iv = invS[q];
    U64v o;
    o.x = (uint32_t)f2bf(s0 * iv) | ((uint32_t)f2bf(s1 * iv) << 16);
    o.y = (uint32_t)f2bf(s2 * iv) | ((uint32_t)f2bf(s3 * iv) << 16);
    *(U64v*)&Out[obase + db * 16] = o;
  }
}

extern "C" void kernel_launch(void* const* d_in, const int* in_sizes, int n_in,
                              void* d_out, int out_size, void* d_ws, size_t ws_size,
                              hipStream_t stream) {
  (void)in_sizes; (void)n_in; (void)out_size; (void)ws_size;
  const float* x        = (const float*)d_in[0];
  const float* rope_cos = (const float*)d_in[1];
  const float* rope_sin = (const float*)d_in[2];
  const float* W_qkv    = (const float*)d_in[3];
  const float* b_qkv    = (const float*)d_in[4];
  const float* W_proj   = (const float*)d_in[5];
  const float* b_proj   = (const float*)d_in[6];
  const int*   nsp      = (const int*)d_in[7];
  float* out = (float*)d_out;

  char* ws = (char*)d_ws;
  u16* Xb   = (u16*)(ws);              // 8192x768 bf16
  u16* Wqkt = (u16*)(ws + 12582912);   // 2304x768 bf16
  u16* Wpt  = (u16*)(ws + 16121856);   // 768x768 bf16
  u16* Qb   = (u16*)(ws + 55050240);   // 48x2048x64 bf16
  u16* Kb   = (u16*)(ws + 67633152);
  u16* Vtb  = (u16*)(ws + 80216064);   // 48x64x2048 bf16
  u16* att  = (u16*)(ws + 92798976);   // 8192x768 bf16

  cvt_f32_bf16<<<6144, 256, 0, stream>>>(x, Xb);
  transpose_cvt<<<dim3(72, 24), 256, 0, stream>>>(W_qkv, Wqkt, 768, 2304);
  transpose_cvt<<<dim3(24, 24), 256, 0, stream>>>(W_proj, Wpt, 768, 768);
  gemm_qkv_rope<<<dim3(18, 64), 256, 0, stream>>>(Xb, Wqkt, b_qkv, rope_cos, rope_sin,
                                                  nsp, Qb, Kb, Vtb);
  attn<<<768, 256, 0, stream>>>(Qb, Kb, Vtb, att, 0);
  attn<<<768, 256, 0, stream>>>(Qb, Kb, Vtb, att, 16);
  gemm_bt<<<dim3(6, 64), 256, 0, stream>>>(att, Wpt, b_proj, out, 8192, 768, 768);
}